// Round 4
// baseline (301.125 us; speedup 1.0000x reference)
//
#include <hip/hip_runtime.h>
#include <hip/hip_bf16.h>

#define N_    1024
#define L_    120
#define LQ_   30
#define D_    200
#define P_    5
#define H_    230
#define R_    96
#define BAG_  8
#define B_    128
#define EMB_  610
#define SROWS 132      // s rows: row 0 = pos -1 (zero), 1..120 = pos 0..119, 121+ zero
#define SSTR  224      // s stride (shorts): 112dw%32=16 -> uniform banks for b128
#define NCHUNK 22      // conv K re-blocked: 7 x1 + 7 x2 + 7 x3 + 1 pos (each comp zero-padded to 224)

typedef __hip_bfloat16 bf16;
typedef __attribute__((ext_vector_type(8))) short short8;
typedef __attribute__((ext_vector_type(4))) short short4_;
typedef __attribute__((ext_vector_type(4))) float f32x4;

__device__ __forceinline__ float wred_sum64(float v) {
#pragma unroll
  for (int m = 32; m; m >>= 1) v += __shfl_xor(v, m, 64);
  return v;
}
__device__ __forceinline__ float wred_max64(float v) {
#pragma unroll
  for (int m = 32; m; m >>= 1) v = fmaxf(v, __shfl_xor(v, m, 64));
  return v;
}
__device__ __forceinline__ short f2b(float f) {
  bf16 h = __float2bfloat16(f);
  return __builtin_bit_cast(short, h);
}

// ---------------------------------------------------------------------------
// K0: repack conv_w f32 [H][EMB][3] -> bf16 frag-ready wt[k][cb=22][ni=16][lane][8]
// channel remap: cb 0..6 -> x1 d=32*cb+ccl (<200), 7..13 -> x2, 14..20 -> x3,
// cb 21 -> pos (ccl<10). Out-of-range channels are zero.
// ---------------------------------------------------------------------------
__global__ __launch_bounds__(256) void k0_prep_w(
    const float* __restrict__ conv_w, bf16* __restrict__ wt)
{
  const int idx = blockIdx.x * 256 + threadIdx.x;   // grid covers 3*22*16*64*8 exactly
  int e = idx & 7, lane = (idx >> 3) & 63;
  int fid = idx >> 9;
  int ni = fid & 15, cb = (fid >> 4) % NCHUNK, k = fid / (NCHUNK * 16);
  int h = ni * 16 + (lane & 15);
  int ccl = ((lane >> 4) << 3) + e;                 // 0..31 within chunk
  float v = 0.f;
  if (h < H_) {
    int emb_c = -1;
    if (cb < 21) {
      int comp = cb / 7;
      int ld = (cb % 7) * 32 + ccl;
      if (ld < D_) emb_c = comp * D_ + ld;
    } else if (ccl < 2 * P_) {
      emb_c = 3 * D_ + ccl;
    }
    if (emb_c >= 0) v = conv_w[(size_t)h * (EMB_ * 3) + emb_c * 3 + k];
  }
  wt[idx] = __float2bfloat16(v);
}

// ---------------------------------------------------------------------------
// KF: fused qs-attention + conv1d(k=3,SAME) + maxpool + relu -> feat [N][H]
// grid = N_, block = 512 (8 waves). x never goes to global memory.
//  A: gather word_emb -> s_lds (bf16) + sdot; q -> qsw (q*wsq), qT, qdot
//  B: GEMM1 h = s @ qsw^T (MFMA), lane-parallel row softmax -> a_bf, hmax
//  C: bvec = softmax_l(hmax); q2s = bvec @ s; zero x23 (union w/ dead qsw)
//  conv part 1+2: 7 chunks, A = s_lds; B = wt[x1 chunk] and wt[x3 chunk]*q2s
//  conv part 3: 7 chunks, GEMM2 s2q = a@qT -> x23 = s*s2q -> conv-step
//  conv part 4: pos chunk via x23
//  epilogue: max over pos, +bias, relu -> feat
// ---------------------------------------------------------------------------
__global__ __launch_bounds__(512, 2) void kf_fused(
    const int* __restrict__ X, const int* __restrict__ Q,
    const int* __restrict__ P1, const int* __restrict__ P2,
    const float* __restrict__ word_emb,
    const float* __restrict__ pos1_emb, const float* __restrict__ pos2_emb,
    const float* __restrict__ ws_w, const float* __restrict__ ws_b,
    const float* __restrict__ wq_w, const float* __restrict__ wq_b,
    const float* __restrict__ wsq_w,
    const bf16* __restrict__ wt, const float* __restrict__ conv_b,
    float* __restrict__ feat)
{
  const int n = blockIdx.x;
  const int tid = threadIdx.x;
  const int w = tid >> 6, lane = tid & 63;
  const int g = lane >> 4, c = lane & 15;
  const int wm = w >> 2, wn = w & 3;

  __shared__ bf16 s_lds[SROWS][SSTR];          // 59.1 KB
  __shared__ bf16 qT[224][40];                 // 17.9 KB  qT[d][j] = q[j][d]
  __shared__ bf16 a_bf[128][40];               // 10.2 KB  attn weights, A-frag layout
  __shared__ long long uni8[32 * SSTR * 2 / 8];// 14.3 KB  qsw | x23 + hred
  __shared__ float wsv[D_], wqv[D_], wsqv[D_];
  __shared__ float sdot[128], qdot[32], hmax[128], bvec[L_], q2s[224];

  bf16 (*qsw)[SSTR] = (bf16(*)[SSTR])uni8;     // [32][224], dead after GEMM1
  bf16 (*x23)[40]   = (bf16(*)[40])uni8;       // [132][40], conv staging
  float (*hred)[64] = (float(*)[64])((char*)uni8 + SROWS * 40 * 2);  // disjoint from x23

  // ---- zero init ----
  for (int t = tid; t < SROWS * SSTR / 2; t += 512) ((int*)s_lds)[t] = 0;
  for (int t = tid; t < 224 * 40 / 2; t += 512) ((int*)qT)[t] = 0;
  for (int t = tid; t < 32 * SSTR / 2; t += 512) ((int*)uni8)[t] = 0;
  for (int t = tid; t < 224; t += 512) q2s[t] = 0.f;
  if (tid < 128) sdot[tid] = 0.f;
  if (tid < 32) qdot[tid] = 0.f;
  for (int t = tid; t < D_; t += 512) { wsv[t] = ws_w[t]; wqv[t] = wq_w[t]; wsqv[t] = wsq_w[t]; }
  __syncthreads();

  const float wsb = ws_b[0], wqb = wq_b[0];

  // ---- phase A: gathers ----
  for (int l = w; l < L_; l += 8) {
    const int idx = X[n * L_ + l];
    float part = 0.f;
    if (lane < 50) {
      const int d = lane * 4;
      float4 v = *(const float4*)(word_emb + (size_t)idx * D_ + d);
      part = v.x * wsv[d] + v.y * wsv[d + 1] + v.z * wsv[d + 2] + v.w * wsv[d + 3];
      short4_ pk; pk.x = f2b(v.x); pk.y = f2b(v.y); pk.z = f2b(v.z); pk.w = f2b(v.w);
      *(short4_*)&s_lds[1 + l][d] = pk;
    }
    float sum = wred_sum64(part);
    if (lane == 0) sdot[l] = sum + wsb;
  }
  for (int j = w; j < LQ_; j += 8) {
    const int idx = Q[n * LQ_ + j];
    float part = 0.f;
    if (lane < 50) {
      const int d = lane * 4;
      float4 v = *(const float4*)(word_emb + (size_t)idx * D_ + d);
      part = v.x * wqv[d] + v.y * wqv[d + 1] + v.z * wqv[d + 2] + v.w * wqv[d + 3];
      short4_ pk;
      pk.x = f2b(v.x * wsqv[d]);     pk.y = f2b(v.y * wsqv[d + 1]);
      pk.z = f2b(v.z * wsqv[d + 2]); pk.w = f2b(v.w * wsqv[d + 3]);
      *(short4_*)&qsw[j][d] = pk;
      qT[d][j]     = __float2bfloat16(v.x);
      qT[d + 1][j] = __float2bfloat16(v.y);
      qT[d + 2][j] = __float2bfloat16(v.z);
      qT[d + 3][j] = __float2bfloat16(v.w);
    }
    float sum = wred_sum64(part);
    if (lane == 0) qdot[j] = sum + wqb;
  }
  __syncthreads();

  // ---- phase B: GEMM1 + softmax ----
  {
    f32x4 acc0 = {0.f, 0.f, 0.f, 0.f}, acc1 = {0.f, 0.f, 0.f, 0.f};
#pragma unroll
    for (int kk = 0; kk < 7; ++kk) {
      short8 af = *(const short8*)&s_lds[1 + 16 * w + c][kk * 32 + g * 8];
      short8 b0 = *(const short8*)&qsw[c][kk * 32 + g * 8];
      short8 b1 = *(const short8*)&qsw[16 + c][kk * 32 + g * 8];
      acc0 = __builtin_amdgcn_mfma_f32_16x16x32_bf16(af, b0, acc0, 0, 0, 0);
      acc1 = __builtin_amdgcn_mfma_f32_16x16x32_bf16(af, b1, acc1, 0, 0, 0);
    }
    const int rbase = 16 * w + 4 * g;
    const float qd0 = qdot[c], qd1 = qdot[16 + c];
#pragma unroll
    for (int reg = 0; reg < 4; ++reg) {
      const int r = rbase + reg;
      const float s0 = sdot[r];
      float h0 = acc0[reg] + s0 + qd0;
      float h1 = (c < 14) ? (acc1[reg] + s0 + qd1) : -1e30f;
      float m = fmaxf(h0, h1);
#pragma unroll
      for (int msk = 1; msk < 16; msk <<= 1) m = fmaxf(m, __shfl_xor(m, msk, 64));
      float e0 = expf(h0 - m);
      float e1 = (c < 14) ? expf(h1 - m) : 0.f;
      float ssum = e0 + e1;
#pragma unroll
      for (int msk = 1; msk < 16; msk <<= 1) ssum += __shfl_xor(ssum, msk, 64);
      float inv = 1.f / ssum;
      a_bf[r][c]      = __float2bfloat16(e0 * inv);
      a_bf[r][16 + c] = __float2bfloat16(e1 * inv);
      if (c == 0) hmax[r] = m;
    }
  }
  __syncthreads();

  // ---- phase C: bvec (wave 0) + zero x23 (qsw dead) ----
  if (w == 0) {
    float v0 = hmax[lane];
    float v1 = (lane < L_ - 64) ? hmax[64 + lane] : -1e30f;
    float m = wred_max64(fmaxf(v0, v1));
    float e0 = expf(v0 - m);
    float e1 = (lane < L_ - 64) ? expf(v1 - m) : 0.f;
    float inv = 1.f / wred_sum64(e0 + e1);
    bvec[lane] = e0 * inv;
    if (lane < L_ - 64) bvec[64 + lane] = e1 * inv;
  }
  for (int t = tid; t < SROWS * 40 / 2; t += 512) ((int*)x23)[t] = 0;
  __syncthreads();
  if (tid < D_) {
    float acc = 0.f;
#pragma unroll 4
    for (int l = 0; l < L_; ++l)
      acc += bvec[l] * __bfloat162float(s_lds[1 + l][tid]);
    q2s[tid] = acc;
  }
  __syncthreads();

  // ---- conv ----
  const short* wts = (const short*)wt;
  f32x4 acc[4][4];
#pragma unroll
  for (int i = 0; i < 4; ++i)
#pragma unroll
    for (int j = 0; j < 4; ++j) acc[i][j] = (f32x4){0.f, 0.f, 0.f, 0.f};

  // part 1+2: x1 chunks (B = wt) and x3 chunks (B = wt * q2s), A = s_lds
  for (int i = 0; i < 7; ++i) {
    const int c0 = i * 32;
    short8 af[3][4];
#pragma unroll
    for (int k = 0; k < 3; ++k)
#pragma unroll
      for (int mi = 0; mi < 4; ++mi)
        af[k][mi] = *(const short8*)&s_lds[wm * 64 + mi * 16 + c + k][c0 + g * 8];
    float q8[8];
#pragma unroll
    for (int e = 0; e < 8; ++e) q8[e] = q2s[c0 + g * 8 + e];
#pragma unroll
    for (int k = 0; k < 3; ++k) {
#pragma unroll
      for (int ni = 0; ni < 4; ++ni) {
        const short8 b1 = *(const short8*)(
            wts + (((size_t)((k * NCHUNK + i) * 16 + wn * 4 + ni)) << 9) + lane * 8);
#pragma unroll
        for (int mi = 0; mi < 4; ++mi)
          acc[mi][ni] = __builtin_amdgcn_mfma_f32_16x16x32_bf16(af[k][mi], b1, acc[mi][ni], 0, 0, 0);
        const short8 b2r = *(const short8*)(
            wts + (((size_t)((k * NCHUNK + 14 + i) * 16 + wn * 4 + ni)) << 9) + lane * 8);
        short8 b2;
#pragma unroll
        for (int e = 0; e < 8; ++e)
          b2[e] = f2b(__bfloat162float(__builtin_bit_cast(bf16, (short)b2r[e])) * q8[e]);
#pragma unroll
        for (int mi = 0; mi < 4; ++mi)
          acc[mi][ni] = __builtin_amdgcn_mfma_f32_16x16x32_bf16(af[k][mi], b2, acc[mi][ni], 0, 0, 0);
      }
    }
  }

  // part 3: x2 chunks via GEMM2 + x23 staging
  const short8 aft = *(const short8*)&a_bf[16 * w + c][g * 8];
  for (int i = 0; i < 7; ++i) {
#pragma unroll
    for (int sub = 0; sub < 2; ++sub) {
      const int nt = 2 * i + sub;
      short8 bfr = *(const short8*)&qT[nt * 16 + c][g * 8];
      f32x4 o = __builtin_amdgcn_mfma_f32_16x16x32_bf16(aft, bfr, (f32x4){0.f,0.f,0.f,0.f}, 0, 0, 0);
#pragma unroll
      for (int reg = 0; reg < 4; ++reg) {
        const int r = 16 * w + 4 * g + reg;
        if (r < L_) {
          float sval = __bfloat162float(s_lds[1 + r][nt * 16 + c]);
          x23[1 + r][sub * 16 + c] = __float2bfloat16(sval * o[reg]);
        }
      }
    }
    __syncthreads();
#pragma unroll
    for (int k = 0; k < 3; ++k) {
      short8 afx[4];
#pragma unroll
      for (int mi = 0; mi < 4; ++mi)
        afx[mi] = *(const short8*)&x23[wm * 64 + mi * 16 + c + k][g * 8];
#pragma unroll
      for (int ni = 0; ni < 4; ++ni) {
        const short8 bf1 = *(const short8*)(
            wts + (((size_t)((k * NCHUNK + 7 + i) * 16 + wn * 4 + ni)) << 9) + lane * 8);
#pragma unroll
        for (int mi = 0; mi < 4; ++mi)
          acc[mi][ni] = __builtin_amdgcn_mfma_f32_16x16x32_bf16(afx[mi], bf1, acc[mi][ni], 0, 0, 0);
      }
    }
    __syncthreads();
  }

  // part 4: pos chunk
  for (int t = tid; t < SROWS * 32; t += 512) {
    int r = t >> 5, cc = t & 31;
    float v = 0.f;
    if (r >= 1 && r <= L_ && cc < 2 * P_) {
      int l = r - 1;
      v = (cc < P_) ? pos1_emb[(size_t)P1[n * L_ + l] * P_ + cc]
                    : pos2_emb[(size_t)P2[n * L_ + l] * P_ + (cc - P_)];
    }
    x23[r][cc] = __float2bfloat16(v);
  }
  __syncthreads();
#pragma unroll
  for (int k = 0; k < 3; ++k) {
    short8 afx[4];
#pragma unroll
    for (int mi = 0; mi < 4; ++mi)
      afx[mi] = *(const short8*)&x23[wm * 64 + mi * 16 + c + k][g * 8];
#pragma unroll
    for (int ni = 0; ni < 4; ++ni) {
      const short8 bf1 = *(const short8*)(
          wts + (((size_t)((k * NCHUNK + 21) * 16 + wn * 4 + ni)) << 9) + lane * 8);
#pragma unroll
      for (int mi = 0; mi < 4; ++mi)
        acc[mi][ni] = __builtin_amdgcn_mfma_f32_16x16x32_bf16(afx[mi], bf1, acc[mi][ni], 0, 0, 0);
    }
  }

  // ---- epilogue: max over pos, +bias, relu ----
  const int pbase = wm * 64 + (g << 2);
#pragma unroll
  for (int ni = 0; ni < 4; ++ni) {
    float m = -1e30f;
#pragma unroll
    for (int mi = 0; mi < 4; ++mi)
#pragma unroll
      for (int reg = 0; reg < 4; ++reg) {
        int pos = pbase + mi * 16 + reg;
        if (pos < L_) m = fmaxf(m, acc[mi][ni][reg]);
      }
    m = fmaxf(m, __shfl_xor(m, 16, 64));
    m = fmaxf(m, __shfl_xor(m, 32, 64));
    if (g == 0) hred[w][ni * 16 + c] = m;
  }
  __syncthreads();
  for (int h = tid; h < H_; h += 512) {
    int wn2 = h >> 6, hl = h & 63;
    float m = fmaxf(hred[wn2][hl], hred[wn2 + 4][hl]);
    feat[(size_t)n * H_ + h] = fmaxf(0.f, m + conv_b[h]);
  }
}

// ---------------------------------------------------------------------------
// K3: bag self-attention + selective attention + final projection -> out [B][R]
// ---------------------------------------------------------------------------
__global__ __launch_bounds__(256) void k3_bag(
    const float* __restrict__ feat, const int* __restrict__ X_Rel,
    const float* __restrict__ rel_w, const float* __restrict__ rel_b,
    float* __restrict__ out)
{
  const int b = blockIdx.x;
  const int tid = threadIdx.x;
  __shared__ float f[BAG_][231];
  __shared__ float f2[BAG_][231];
  __shared__ float sc[BAG_][BAG_];
  __shared__ float relq[H_];
  __shared__ float zred[BAG_];
  __shared__ float wsel[BAG_];
  __shared__ float brep[H_];

  for (int t = tid; t < BAG_ * H_; t += 256) {
    int i = t / H_, h = t % H_;
    f[i][h] = feat[(size_t)(b * BAG_ + i) * H_ + h];
  }
  const int rel = X_Rel[b];
  for (int t = tid; t < H_; t += 256) relq[t] = rel_w[(size_t)rel * H_ + t];
  __syncthreads();

  if (tid < BAG_ * BAG_) {
    int i = tid >> 3, j = tid & 7;
    float acc = 0.f;
    for (int h = 0; h < H_; ++h) acc += f[i][h] * f[j][h];
    sc[i][j] = acc * (1.0f / sqrtf((float)H_));
  }
  __syncthreads();
  if (tid < BAG_) {
    float m = -1e30f;
    for (int j = 0; j < BAG_; ++j) m = fmaxf(m, sc[tid][j]);
    float s = 0.f;
    for (int j = 0; j < BAG_; ++j) { float e = expf(sc[tid][j] - m); sc[tid][j] = e; s += e; }
    float inv = 1.0f / s;
    for (int j = 0; j < BAG_; ++j) sc[tid][j] *= inv;
  }
  __syncthreads();
  for (int t = tid; t < BAG_ * H_; t += 256) {
    int i = t / H_, h = t % H_;
    float acc = 0.f;
#pragma unroll
    for (int j = 0; j < BAG_; ++j) acc += sc[i][j] * f[j][h];
    f2[i][h] = acc;
  }
  __syncthreads();
  if (tid < BAG_) {
    float acc = 0.f;
    for (int h = 0; h < H_; ++h) acc += f2[tid][h] * relq[h];
    zred[tid] = acc;
  }
  __syncthreads();
  if (tid == 0) {
    float m = -1e30f;
    for (int i = 0; i < BAG_; ++i) m = fmaxf(m, zred[i]);
    float s = 0.f;
    for (int i = 0; i < BAG_; ++i) { float e = expf(zred[i] - m); wsel[i] = e; s += e; }
    float inv = 1.0f / s;
    for (int i = 0; i < BAG_; ++i) wsel[i] *= inv;
  }
  __syncthreads();
  for (int t = tid; t < H_; t += 256) {
    float acc = 0.f;
#pragma unroll
    for (int i = 0; i < BAG_; ++i) acc += wsel[i] * f2[i][t];
    brep[t] = acc;
  }
  __syncthreads();
  if (tid < R_) {
    float acc = 0.f;
    for (int h = 0; h < H_; ++h) acc += brep[h] * rel_w[(size_t)tid * H_ + h];
    out[(size_t)b * R_ + tid] = acc + rel_b[tid];
  }
}

// ---------------------------------------------------------------------------
extern "C" void kernel_launch(void* const* d_in, const int* in_sizes, int n_in,
                              void* d_out, int out_size, void* d_ws, size_t ws_size,
                              hipStream_t stream)
{
  const int*   X        = (const int*)d_in[0];
  const int*   Q        = (const int*)d_in[1];
  const int*   P1       = (const int*)d_in[2];
  const int*   P2       = (const int*)d_in[3];
  // d_in[4] = X_Scope (uniform bags of 8; bag_id = i/8)
  const int*   X_Rel    = (const int*)d_in[5];
  const float* word_emb = (const float*)d_in[6];
  const float* pos1_emb = (const float*)d_in[7];
  const float* pos2_emb = (const float*)d_in[8];
  const float* ws_w     = (const float*)d_in[9];
  const float* ws_b     = (const float*)d_in[10];
  const float* wq_w     = (const float*)d_in[11];
  const float* wq_b     = (const float*)d_in[12];
  const float* wsq_w    = (const float*)d_in[13];
  // d_in[14] = wsq_b: constant shift of h -> softmax-invariant (both a and bvec), dropped
  const float* conv_w   = (const float*)d_in[15];
  const float* conv_b   = (const float*)d_in[16];
  const float* rel_w    = (const float*)d_in[17];
  const float* rel_b    = (const float*)d_in[18];

  // ws layout: feat f32 [N][H] | wt bf16 [3][22][16][64][8]
  const size_t feat_bytes = ((size_t)N_ * H_ * sizeof(float) + 255) & ~(size_t)255;
  float* feat = (float*)d_ws;
  bf16*  wt   = (bf16*)((char*)d_ws + feat_bytes);

  const int wt_elems = 3 * NCHUNK * 16 * 64 * 8;   // 540672
  k0_prep_w<<<wt_elems / 256, 256, 0, stream>>>(conv_w, wt);
  kf_fused<<<N_, 512, 0, stream>>>(X, Q, P1, P2, word_emb, pos1_emb, pos2_emb,
                                   ws_w, ws_b, wq_w, wq_b, wsq_w, wt, conv_b, feat);
  k3_bag<<<B_, 256, 0, stream>>>(feat, X_Rel, rel_w, rel_b, (float*)d_out);
}

// Round 5
// 299.950 us; speedup vs baseline: 1.0039x; 1.0039x over previous
//
#include <hip/hip_runtime.h>
#include <hip/hip_bf16.h>

#define N_    1024
#define L_    120
#define LQ_   30
#define D_    200
#define P_    5
#define H_    230
#define R_    96
#define BAG_  8
#define B_    128
#define EMB_  610
#define SROWS 132      // s rows: 0 = halo(-1)=0, 1..120 = pos, 121..131 = 0
#define SSTR  232      // 116 dw % 32 = 20 -> 2-way (free) on b128 frag reads
#define XSTR  72       // x23 stride: 36 dw % 32 = 4 -> 2-way; 144B rows, 16B-aligned
#define NCHUNK 22      // conv K chunks: 7 x1 + 7 x2 + 7 x3 + 1 pos

typedef __hip_bfloat16 bf16;
typedef __attribute__((ext_vector_type(8))) short short8;
typedef __attribute__((ext_vector_type(4))) short short4_;
typedef __attribute__((ext_vector_type(4))) float f32x4;

__device__ __forceinline__ float wred_sum64(float v) {
#pragma unroll
  for (int m = 32; m; m >>= 1) v += __shfl_xor(v, m, 64);
  return v;
}
__device__ __forceinline__ float wred_max64(float v) {
#pragma unroll
  for (int m = 32; m; m >>= 1) v = fmaxf(v, __shfl_xor(v, m, 64));
  return v;
}
__device__ __forceinline__ short f2b(float f) {
  bf16 h = __float2bfloat16(f);
  return __builtin_bit_cast(short, h);
}

// ---------------------------------------------------------------------------
// K0: repack conv_w f32 [H][EMB][3] -> bf16 frag-ready wt[k][cb=22][ni=16][lane][8]
// cb 0..6 -> x1 (d=32*cb'+ccl), 7..13 -> x2, 14..20 -> x3, 21 -> pos (ccl<10).
// ---------------------------------------------------------------------------
__global__ __launch_bounds__(256) void k0_prep_w(
    const float* __restrict__ conv_w, bf16* __restrict__ wt)
{
  const int idx = blockIdx.x * 256 + threadIdx.x;
  int e = idx & 7, lane = (idx >> 3) & 63;
  int fid = idx >> 9;
  int ni = fid & 15, cb = (fid >> 4) % NCHUNK, k = fid / (NCHUNK * 16);
  int h = ni * 16 + (lane & 15);
  int ccl = ((lane >> 4) << 3) + e;
  float v = 0.f;
  if (h < H_) {
    int emb_c = -1;
    if (cb < 21) {
      int comp = cb / 7;
      int ld = (cb % 7) * 32 + ccl;
      if (ld < D_) emb_c = comp * D_ + ld;
    } else if (ccl < 2 * P_) {
      emb_c = 3 * D_ + ccl;
    }
    if (emb_c >= 0) v = conv_w[(size_t)h * (EMB_ * 3) + emb_c * 3 + k];
  }
  wt[idx] = __float2bfloat16(v);
}

// ---------------------------------------------------------------------------
// KF: fused qs-attention + conv1d(k=3,SAME) + maxpool + relu -> feat [N][H]
// grid = N_, block = 512 (8 waves). x never touches global memory.
// ---------------------------------------------------------------------------
__global__ __launch_bounds__(512) void kf_fused(
    const int* __restrict__ X, const int* __restrict__ Q,
    const int* __restrict__ P1, const int* __restrict__ P2,
    const float* __restrict__ word_emb,
    const float* __restrict__ pos1_emb, const float* __restrict__ pos2_emb,
    const float* __restrict__ ws_w, const float* __restrict__ ws_b,
    const float* __restrict__ wq_w, const float* __restrict__ wq_b,
    const float* __restrict__ wsq_w,
    const bf16* __restrict__ wt, const float* __restrict__ conv_b,
    float* __restrict__ feat)
{
  const int n = blockIdx.x;
  const int tid = threadIdx.x;
  const int w = tid >> 6, lane = tid & 63;
  const int g = lane >> 4, c = lane & 15;
  const int wm = w >> 2, wn = w & 3;

  __shared__ bf16 s_lds[SROWS][SSTR];          // 61.2 KB
  __shared__ bf16 qT[224][40];                 // 17.9 KB  qT[d][j] = q[j][d]
  __shared__ bf16 a_bf[128][40];               // 10.2 KB  attn weights (A-frag layout)
  __shared__ long long uni8[19008 / 8];        // 19.0 KB  qsw[32][232] | x23[132][72]
  __shared__ float hred[8][64];
  __shared__ float wsv[D_], wqv[D_], wsqv[D_];
  __shared__ float sdot[128], qdot[32], hmax[128], bvec[L_];
  __shared__ float q2p[2][224];
  __shared__ int xidxs[L_], qidxs[LQ_];

  bf16 (*qsw)[SSTR] = (bf16(*)[SSTR])uni8;     // live only through GEMM1
  bf16 (*x23)[XSTR] = (bf16(*)[XSTR])uni8;     // conv staging afterwards

  // ---- zero init ----
  for (int t = tid; t < SROWS * SSTR / 2; t += 512) ((int*)s_lds)[t] = 0;
  for (int t = tid; t < 224 * 40 / 2; t += 512) ((int*)qT)[t] = 0;
  for (int t = tid; t < 32 * SSTR / 2; t += 512) ((int*)qsw)[t] = 0;
  if (tid < 128) sdot[tid] = 0.f;
  if (tid < 32) qdot[tid] = 0.f;
  for (int t = tid; t < D_; t += 512) { wsv[t] = ws_w[t]; wqv[t] = wq_w[t]; wsqv[t] = wsq_w[t]; }
  if (tid < L_) xidxs[tid] = X[n * L_ + tid];
  else if (tid >= 128 && tid < 128 + LQ_) qidxs[tid - 128] = Q[n * LQ_ + (tid - 128)];
  __syncthreads();

  const float wsb = ws_b[0], wqb = wq_b[0];

  // ---- phase A: gathers (indices from LDS -> single-load dep chain) ----
#pragma unroll 3
  for (int l = w; l < L_; l += 8) {
    const int idx = xidxs[l];
    float part = 0.f;
    if (lane < 50) {
      const int d = lane * 4;
      float4 v = *(const float4*)(word_emb + (size_t)idx * D_ + d);
      part = v.x * wsv[d] + v.y * wsv[d + 1] + v.z * wsv[d + 2] + v.w * wsv[d + 3];
      short4_ pk; pk.x = f2b(v.x); pk.y = f2b(v.y); pk.z = f2b(v.z); pk.w = f2b(v.w);
      *(short4_*)&s_lds[1 + l][d] = pk;
    }
    float sum = wred_sum64(part);
    if (lane == 0) sdot[l] = sum + wsb;
  }
  for (int j = w; j < LQ_; j += 8) {
    const int idx = qidxs[j];
    float part = 0.f;
    if (lane < 50) {
      const int d = lane * 4;
      float4 v = *(const float4*)(word_emb + (size_t)idx * D_ + d);
      part = v.x * wqv[d] + v.y * wqv[d + 1] + v.z * wqv[d + 2] + v.w * wqv[d + 3];
      short4_ pk;
      pk.x = f2b(v.x * wsqv[d]);     pk.y = f2b(v.y * wsqv[d + 1]);
      pk.z = f2b(v.z * wsqv[d + 2]); pk.w = f2b(v.w * wsqv[d + 3]);
      *(short4_*)&qsw[j][d] = pk;
      qT[d][j]     = __float2bfloat16(v.x);
      qT[d + 1][j] = __float2bfloat16(v.y);
      qT[d + 2][j] = __float2bfloat16(v.z);
      qT[d + 3][j] = __float2bfloat16(v.w);
    }
    float sum = wred_sum64(part);
    if (lane == 0) qdot[j] = sum + wqb;
  }
  __syncthreads();

  // ---- phase B: GEMM1 h = s @ (q*wsq)^T + lane-parallel row softmax ----
  {
    f32x4 acc0 = {0.f, 0.f, 0.f, 0.f}, acc1 = {0.f, 0.f, 0.f, 0.f};
#pragma unroll
    for (int kk = 0; kk < 7; ++kk) {
      short8 af = *(const short8*)&s_lds[1 + 16 * w + c][kk * 32 + g * 8];
      short8 b0 = *(const short8*)&qsw[c][kk * 32 + g * 8];
      short8 b1 = *(const short8*)&qsw[16 + c][kk * 32 + g * 8];
      acc0 = __builtin_amdgcn_mfma_f32_16x16x32_bf16(af, b0, acc0, 0, 0, 0);
      acc1 = __builtin_amdgcn_mfma_f32_16x16x32_bf16(af, b1, acc1, 0, 0, 0);
    }
    const int rbase = 16 * w + 4 * g;
    const float qd0 = qdot[c], qd1 = qdot[16 + c];
#pragma unroll
    for (int reg = 0; reg < 4; ++reg) {
      const int r = rbase + reg;
      const float s0 = sdot[r];
      float h0 = acc0[reg] + s0 + qd0;
      float h1 = (c < 14) ? (acc1[reg] + s0 + qd1) : -1e30f;
      float m = fmaxf(h0, h1);
#pragma unroll
      for (int msk = 1; msk < 16; msk <<= 1) m = fmaxf(m, __shfl_xor(m, msk, 64));
      float e0 = expf(h0 - m);
      float e1 = (c < 14) ? expf(h1 - m) : 0.f;
      float ssum = e0 + e1;
#pragma unroll
      for (int msk = 1; msk < 16; msk <<= 1) ssum += __shfl_xor(ssum, msk, 64);
      float inv = 1.f / ssum;
      a_bf[r][c]      = __float2bfloat16(e0 * inv);
      a_bf[r][16 + c] = __float2bfloat16(e1 * inv);
      if (c == 0) hmax[r] = m;
    }
  }
  __syncthreads();   // a_bf/hmax ready; qsw dead from here

  // ---- phase C: bvec (wave 0) while others zero x23; then q2s halves ----
  if (w == 0) {
    float v0 = hmax[lane];
    float v1 = (lane < L_ - 64) ? hmax[64 + lane] : -1e30f;
    float m = wred_max64(fmaxf(v0, v1));
    float e0 = expf(v0 - m);
    float e1 = (lane < L_ - 64) ? expf(v1 - m) : 0.f;
    float inv = 1.f / wred_sum64(e0 + e1);
    bvec[lane] = e0 * inv;
    if (lane < L_ - 64) bvec[64 + lane] = e1 * inv;
  } else {
    for (int t = tid - 64; t < 19008 / 8; t += 448) uni8[t] = 0;
  }
  __syncthreads();
  {
    const int d = tid & 255, half = tid >> 8;
    if (d < 224 && half < 2) {
      const int lb = half * 60;
      float a0 = 0.f, a1 = 0.f, a2 = 0.f, a3 = 0.f;
      for (int l = 0; l < 60; l += 4) {
        a0 += bvec[lb + l]     * __bfloat162float(s_lds[1 + lb + l][d]);
        a1 += bvec[lb + l + 1] * __bfloat162float(s_lds[1 + lb + l + 1][d]);
        a2 += bvec[lb + l + 2] * __bfloat162float(s_lds[1 + lb + l + 2][d]);
        a3 += bvec[lb + l + 3] * __bfloat162float(s_lds[1 + lb + l + 3][d]);
      }
      q2p[half][d] = (a0 + a1) + (a2 + a3);
    }
  }
  __syncthreads();

  // ---- conv part 1: x1 chunks, A straight from s_lds ----
  const short* wts = (const short*)wt;
  f32x4 acc[4][4];
#pragma unroll
  for (int i = 0; i < 4; ++i)
#pragma unroll
    for (int j = 0; j < 4; ++j) acc[i][j] = (f32x4){0.f, 0.f, 0.f, 0.f};

  for (int i = 0; i < 7; ++i) {
    short8 af[3][4];
#pragma unroll
    for (int k = 0; k < 3; ++k)
#pragma unroll
      for (int mi = 0; mi < 4; ++mi)
        af[k][mi] = *(const short8*)&s_lds[wm * 64 + mi * 16 + c + k][i * 32 + g * 8];
#pragma unroll
    for (int k = 0; k < 3; ++k)
#pragma unroll
      for (int ni = 0; ni < 4; ++ni) {
        const short8 b1 = *(const short8*)(
            wts + (((size_t)((k * NCHUNK + i) * 16 + wn * 4 + ni)) << 9) + lane * 8);
#pragma unroll
        for (int mi = 0; mi < 4; ++mi)
          acc[mi][ni] = __builtin_amdgcn_mfma_f32_16x16x32_bf16(af[k][mi], b1, acc[mi][ni], 0, 0, 0);
      }
  }

  // ---- conv part 2+3: per 32-chan chunk stage {x2 via GEMM2, x3 = s*q2s} then conv both ----
  const short8 aft = *(const short8*)&a_bf[16 * w + c][g * 8];
  for (int i = 0; i < 7; ++i) {
#pragma unroll
    for (int sub = 0; sub < 2; ++sub) {
      const int nt = 2 * i + sub;
      short8 bfr = *(const short8*)&qT[nt * 16 + c][g * 8];
      f32x4 o = __builtin_amdgcn_mfma_f32_16x16x32_bf16(aft, bfr, (f32x4){0.f,0.f,0.f,0.f}, 0, 0, 0);
#pragma unroll
      for (int reg = 0; reg < 4; ++reg) {
        const int r = 16 * w + 4 * g + reg;
        if (r < L_) {
          float sval = __bfloat162float(s_lds[1 + r][nt * 16 + c]);
          x23[1 + r][sub * 16 + c] = __float2bfloat16(sval * o[reg]);
        }
      }
    }
    for (int t = tid; t < L_ * 32; t += 512) {
      const int row = t >> 5, cc = t & 31;
      const int dd = i * 32 + cc;
      float sv = __bfloat162float(s_lds[1 + row][dd]);
      x23[1 + row][32 + cc] = __float2bfloat16(sv * (q2p[0][dd] + q2p[1][dd]));
    }
    __syncthreads();
#pragma unroll
    for (int half = 0; half < 2; ++half) {
      short8 afx[3][4];
#pragma unroll
      for (int k = 0; k < 3; ++k)
#pragma unroll
        for (int mi = 0; mi < 4; ++mi)
          afx[k][mi] = *(const short8*)&x23[wm * 64 + mi * 16 + c + k][half * 32 + g * 8];
      const int cb = 7 * (1 + half) + i;
#pragma unroll
      for (int k = 0; k < 3; ++k)
#pragma unroll
        for (int ni = 0; ni < 4; ++ni) {
          const short8 b1 = *(const short8*)(
              wts + (((size_t)((k * NCHUNK + cb) * 16 + wn * 4 + ni)) << 9) + lane * 8);
#pragma unroll
          for (int mi = 0; mi < 4; ++mi)
            acc[mi][ni] = __builtin_amdgcn_mfma_f32_16x16x32_bf16(afx[k][mi], b1, acc[mi][ni], 0, 0, 0);
        }
    }
    __syncthreads();
  }

  // ---- conv part 4: pos chunk ----
  for (int t = tid; t < SROWS * 32; t += 512) {
    const int r = t >> 5, cc = t & 31;
    float v = 0.f;
    if (r >= 1 && r <= L_ && cc < 2 * P_) {
      const int l = r - 1;
      v = (cc < P_) ? pos1_emb[(size_t)P1[n * L_ + l] * P_ + cc]
                    : pos2_emb[(size_t)P2[n * L_ + l] * P_ + (cc - P_)];
    }
    x23[r][cc] = __float2bfloat16(v);
  }
  __syncthreads();
#pragma unroll
  for (int k = 0; k < 3; ++k) {
    short8 afx[4];
#pragma unroll
    for (int mi = 0; mi < 4; ++mi)
      afx[mi] = *(const short8*)&x23[wm * 64 + mi * 16 + c + k][g * 8];
#pragma unroll
    for (int ni = 0; ni < 4; ++ni) {
      const short8 b1 = *(const short8*)(
          wts + (((size_t)((k * NCHUNK + 21) * 16 + wn * 4 + ni)) << 9) + lane * 8);
#pragma unroll
      for (int mi = 0; mi < 4; ++mi)
        acc[mi][ni] = __builtin_amdgcn_mfma_f32_16x16x32_bf16(afx[mi], b1, acc[mi][ni], 0, 0, 0);
    }
  }

  // ---- epilogue: max over valid pos, +bias, relu -> feat ----
  const int pbase = wm * 64 + (g << 2);
#pragma unroll
  for (int ni = 0; ni < 4; ++ni) {
    float m = -1e30f;
#pragma unroll
    for (int mi = 0; mi < 4; ++mi)
#pragma unroll
      for (int reg = 0; reg < 4; ++reg) {
        int pos = pbase + mi * 16 + reg;
        if (pos < L_) m = fmaxf(m, acc[mi][ni][reg]);
      }
    m = fmaxf(m, __shfl_xor(m, 16, 64));
    m = fmaxf(m, __shfl_xor(m, 32, 64));
    if (g == 0) hred[w][ni * 16 + c] = m;
  }
  __syncthreads();
  for (int h = tid; h < H_; h += 512) {
    int wn2 = h >> 6, hl = h & 63;
    float m = fmaxf(hred[wn2][hl], hred[wn2 + 4][hl]);
    feat[(size_t)n * H_ + h] = fmaxf(0.f, m + conv_b[h]);
  }
}

// ---------------------------------------------------------------------------
// K3: bag self-attention + selective attention + final projection -> out [B][R]
// ---------------------------------------------------------------------------
__global__ __launch_bounds__(256) void k3_bag(
    const float* __restrict__ feat, const int* __restrict__ X_Rel,
    const float* __restrict__ rel_w, const float* __restrict__ rel_b,
    float* __restrict__ out)
{
  const int b = blockIdx.x;
  const int tid = threadIdx.x;
  __shared__ float f[BAG_][231];
  __shared__ float f2[BAG_][231];
  __shared__ float sc[BAG_][BAG_];
  __shared__ float relq[H_];
  __shared__ float zred[BAG_];
  __shared__ float wsel[BAG_];
  __shared__ float brep[H_];

  for (int t = tid; t < BAG_ * H_; t += 256) {
    int i = t / H_, h = t % H_;
    f[i][h] = feat[(size_t)(b * BAG_ + i) * H_ + h];
  }
  const int rel = X_Rel[b];
  for (int t = tid; t < H_; t += 256) relq[t] = rel_w[(size_t)rel * H_ + t];
  __syncthreads();

  if (tid < BAG_ * BAG_) {
    int i = tid >> 3, j = tid & 7;
    float acc = 0.f;
    for (int h = 0; h < H_; ++h) acc += f[i][h] * f[j][h];
    sc[i][j] = acc * (1.0f / sqrtf((float)H_));
  }
  __syncthreads();
  if (tid < BAG_) {
    float m = -1e30f;
    for (int j = 0; j < BAG_; ++j) m = fmaxf(m, sc[tid][j]);
    float s = 0.f;
    for (int j = 0; j < BAG_; ++j) { float e = expf(sc[tid][j] - m); sc[tid][j] = e; s += e; }
    float inv = 1.0f / s;
    for (int j = 0; j < BAG_; ++j) sc[tid][j] *= inv;
  }
  __syncthreads();
  for (int t = tid; t < BAG_ * H_; t += 256) {
    int i = t / H_, h = t % H_;
    float acc = 0.f;
#pragma unroll
    for (int j = 0; j < BAG_; ++j) acc += sc[i][j] * f[j][h];
    f2[i][h] = acc;
  }
  __syncthreads();
  if (tid < BAG_) {
    float acc = 0.f;
    for (int h = 0; h < H_; ++h) acc += f2[tid][h] * relq[h];
    zred[tid] = acc;
  }
  __syncthreads();
  if (tid == 0) {
    float m = -1e30f;
    for (int i = 0; i < BAG_; ++i) m = fmaxf(m, zred[i]);
    float s = 0.f;
    for (int i = 0; i < BAG_; ++i) { float e = expf(zred[i] - m); wsel[i] = e; s += e; }
    float inv = 1.0f / s;
    for (int i = 0; i < BAG_; ++i) wsel[i] *= inv;
  }
  __syncthreads();
  for (int t = tid; t < H_; t += 256) {
    float acc = 0.f;
#pragma unroll
    for (int i = 0; i < BAG_; ++i) acc += wsel[i] * f2[i][t];
    brep[t] = acc;
  }
  __syncthreads();
  if (tid < R_) {
    float acc = 0.f;
    for (int h = 0; h < H_; ++h) acc += brep[h] * rel_w[(size_t)tid * H_ + h];
    out[(size_t)b * R_ + tid] = acc + rel_b[tid];
  }
}

// ---------------------------------------------------------------------------
extern "C" void kernel_launch(void* const* d_in, const int* in_sizes, int n_in,
                              void* d_out, int out_size, void* d_ws, size_t ws_size,
                              hipStream_t stream)
{
  const int*   X        = (const int*)d_in[0];
  const int*   Q        = (const int*)d_in[1];
  const int*   P1       = (const int*)d_in[2];
  const int*   P2       = (const int*)d_in[3];
  // d_in[4] = X_Scope (uniform bags of 8; bag_id = i/8)
  const int*   X_Rel    = (const int*)d_in[5];
  const float* word_emb = (const float*)d_in[6];
  const float* pos1_emb = (const float*)d_in[7];
  const float* pos2_emb = (const float*)d_in[8];
  const float* ws_w     = (const float*)d_in[9];
  const float* ws_b     = (const float*)d_in[10];
  const float* wq_w     = (const float*)d_in[11];
  const float* wq_b     = (const float*)d_in[12];
  const float* wsq_w    = (const float*)d_in[13];
  // d_in[14] = wsq_b: uniform shift of h -> softmax-invariant (a and bvec), dropped
  const float* conv_w   = (const float*)d_in[15];
  const float* conv_b   = (const float*)d_in[16];
  const float* rel_w    = (const float*)d_in[17];
  const float* rel_b    = (const float*)d_in[18];

  // ws layout: feat f32 [N][H] | wt bf16 [3][22][16][64][8]
  const size_t feat_bytes = ((size_t)N_ * H_ * sizeof(float) + 255) & ~(size_t)255;
  float* feat = (float*)d_ws;
  bf16*  wt   = (bf16*)((char*)d_ws + feat_bytes);

  const int wt_elems = 3 * NCHUNK * 16 * 64 * 8;   // 540672
  k0_prep_w<<<wt_elems / 256, 256, 0, stream>>>(conv_w, wt);
  kf_fused<<<N_, 512, 0, stream>>>(X, Q, P1, P2, word_emb, pos1_emb, pos2_emb,
                                   ws_w, ws_b, wq_w, wq_b, wsq_w, wt, conv_b, feat);
  k3_bag<<<B_, 256, 0, stream>>>(feat, X_Rel, rel_w, rel_b, (float*)d_out);
}

// Round 6
// 233.083 us; speedup vs baseline: 1.2919x; 1.2869x over previous
//
#include <hip/hip_runtime.h>
#include <hip/hip_bf16.h>

#define N_    1024
#define L_    120
#define LQ_   30
#define D_    200
#define P_    5
#define H_    230
#define R_    96
#define BAG_  8
#define B_    128
#define EMB_  610
#define SROWS 130      // s rows: 0 = halo(-1)=0, 1..120 = pos 0..119, 121..129 = 0
#define SSTR  232      // shorts; 464B rows, 16B aligned
#define XSTR  40       // x-stage tile stride (shorts)
#define NCH   21       // conv K chunks: 7 x1 + 13 {x2|x3} mixed + 1 pos

typedef __hip_bfloat16 bf16;
typedef __attribute__((ext_vector_type(8))) short short8;
typedef __attribute__((ext_vector_type(4))) short short4_;
typedef __attribute__((ext_vector_type(4))) float f32x4;

__device__ __forceinline__ float wred_sum64(float v) {
#pragma unroll
  for (int m = 32; m; m >>= 1) v += __shfl_xor(v, m, 64);
  return v;
}
__device__ __forceinline__ float wred_max64(float v) {
#pragma unroll
  for (int m = 32; m; m >>= 1) v = fmaxf(v, __shfl_xor(v, m, 64));
  return v;
}
__device__ __forceinline__ short f2b(float f) {
  bf16 h = __float2bfloat16(f);
  return __builtin_bit_cast(short, h);
}
__device__ __forceinline__ float b2f(bf16 h) { return __bfloat162float(h); }

// ---------------------------------------------------------------------------
// K0: repack conv_w f32 [H][EMB][3] -> bf16 frag-ready wt[k][cb=21][ni=16][lane][8]
//  cb 0..6   : x1 chunk, chan d = cb*32 + ccl (valid d<200)
//  cb 7..19  : mixed tile t=cb-7: ccl<16 -> x2 d=16t+ccl ; ccl>=16 -> x3 d=16t+ccl-16
//  cb 20     : pos, ccl<10 -> emb col 600+ccl
// ---------------------------------------------------------------------------
__global__ __launch_bounds__(256) void k0_prep_w(
    const float* __restrict__ conv_w, bf16* __restrict__ wt)
{
  const int idx = blockIdx.x * 256 + threadIdx.x;   // grid = 3*21*16*512 / 256
  int e = idx & 7, lane = (idx >> 3) & 63;
  int fid = idx >> 9;
  int ni = fid & 15, cb = (fid >> 4) % NCH, k = fid / (NCH * 16);
  int h = ni * 16 + (lane & 15);
  int ccl = ((lane >> 4) << 3) + e;
  float v = 0.f;
  if (h < H_) {
    int emb_c = -1;
    if (cb < 7) {
      int d = cb * 32 + ccl;
      if (d < D_) emb_c = d;
    } else if (cb < 20) {
      int t = cb - 7;
      int d = 16 * t + (ccl & 15);
      if (d < D_) emb_c = (ccl < 16) ? (D_ + d) : (2 * D_ + d);
    } else if (ccl < 2 * P_) {
      emb_c = 3 * D_ + ccl;
    }
    if (emb_c >= 0) v = conv_w[(size_t)h * (EMB_ * 3) + emb_c * 3 + k];
  }
  wt[idx] = __float2bfloat16(v);
}

// ---------------------------------------------------------------------------
// KF: fused qs-attention + conv1d(k=3,SAME) + maxpool + relu -> feat [N][H]
// grid = N_, block = 512 (8 waves). Tri-buffered stage pipeline, 1 barrier/tile.
// ---------------------------------------------------------------------------
__global__ __launch_bounds__(512, 2) void kf_fused(
    const int* __restrict__ X, const int* __restrict__ Q,
    const int* __restrict__ P1, const int* __restrict__ P2,
    const float* __restrict__ word_emb,
    const float* __restrict__ pos1_emb, const float* __restrict__ pos2_emb,
    const float* __restrict__ ws_w, const float* __restrict__ ws_b,
    const float* __restrict__ wq_w, const float* __restrict__ wq_b,
    const float* __restrict__ wsq_w,
    const bf16* __restrict__ wt, const float* __restrict__ conv_b,
    float* __restrict__ feat)
{
  const int n = blockIdx.x;
  const int tid = threadIdx.x;
  const int w = tid >> 6, lane = tid & 63;
  const int g = lane >> 4, c = lane & 15;
  const int wm = w >> 2, wn = w & 3;

  __shared__ __align__(16) bf16 s_lds[SROWS][SSTR];        // 60.3 KB
  __shared__ __align__(16) bf16 qT[208][40];               // 16.6 KB  qT[d][j]
  __shared__ __align__(16) bf16 a_bf[128][40];             // 10.2 KB
  __shared__ __align__(16) bf16 xstage[3][SROWS][XSTR];    // 31.2 KB (overlays qsw)
  __shared__ __align__(16) bf16 pos_lds[L_][10];           //  2.4 KB
  __shared__ float hred[8][64];
  __shared__ float wsv[D_], wqv[D_], wsqv[D_];
  __shared__ float sdot[128], qdot[32], hmax[128], bvec[L_];
  __shared__ float q2p[2][D_];
  __shared__ int xidxs[L_], qidxs[LQ_];

  bf16 (*qsw)[SSTR] = (bf16(*)[SSTR])xstage;   // [32][232], dead after GEMM1

  // ---- zero init (int4 stores) ----
  {
    const int4 z4 = {0, 0, 0, 0};
    for (int t = tid; t < SROWS * SSTR * 2 / 16; t += 512) ((int4*)s_lds)[t] = z4;
    for (int t = tid; t < 208 * 40 * 2 / 16;     t += 512) ((int4*)qT)[t] = z4;
    for (int t = tid; t < 32 * SSTR * 2 / 16;    t += 512) ((int4*)qsw)[t] = z4;
  }
  if (tid < 2) qdot[30 + tid] = 0.f;
  if (tid >= 120 && tid < 128) sdot[tid] = 0.f;
  for (int t = tid; t < D_; t += 512) { wsv[t] = ws_w[t]; wqv[t] = wq_w[t]; wsqv[t] = wsq_w[t]; }
  if (tid < L_) xidxs[tid] = X[n * L_ + tid];
  else if (tid >= 128 && tid < 128 + LQ_) qidxs[tid - 128] = Q[n * LQ_ + (tid - 128)];
  __syncthreads();

  const float wsb = ws_b[0], wqb = wq_b[0];

  // ---- phase A1: independent gathers (no reduction deps) ----
#pragma unroll 5
  for (int l = w; l < L_; l += 8) {
    const int idx = xidxs[l];
    if (lane < 50) {
      const int d = lane * 4;
      float4 v = *(const float4*)(word_emb + (size_t)idx * D_ + d);
      short4_ pk; pk.x = f2b(v.x); pk.y = f2b(v.y); pk.z = f2b(v.z); pk.w = f2b(v.w);
      *(short4_*)&s_lds[1 + l][d] = pk;
    }
  }
  for (int e = tid; e < L_ * 10; e += 512) {
    int r = e / 10, p = e % 10;
    float v = (p < P_) ? pos1_emb[(size_t)P1[n * L_ + r] * P_ + p]
                       : pos2_emb[(size_t)P2[n * L_ + r] * P_ + (p - P_)];
    pos_lds[r][p] = __float2bfloat16(v);
  }
  for (int j = w; j < LQ_; j += 8) {
    const int idx = qidxs[j];
    float part = 0.f;
    if (lane < 50) {
      const int d = lane * 4;
      float4 v = *(const float4*)(word_emb + (size_t)idx * D_ + d);
      part = v.x * wqv[d] + v.y * wqv[d + 1] + v.z * wqv[d + 2] + v.w * wqv[d + 3];
      short4_ pk;
      pk.x = f2b(v.x * wsqv[d]);     pk.y = f2b(v.y * wsqv[d + 1]);
      pk.z = f2b(v.z * wsqv[d + 2]); pk.w = f2b(v.w * wsqv[d + 3]);
      *(short4_*)&qsw[j][d] = pk;
      qT[d][j]     = __float2bfloat16(v.x);
      qT[d + 1][j] = __float2bfloat16(v.y);
      qT[d + 2][j] = __float2bfloat16(v.z);
      qT[d + 3][j] = __float2bfloat16(v.w);
    }
    float sum = wred_sum64(part);
    if (lane == 0) qdot[j] = sum + wqb;
  }
  __syncthreads();

  // ---- phase A2: sdot from LDS (4 lanes per row) ----
  if (tid < 480) {
    const int r = tid >> 2, base = (tid & 3) * 50;
    float a = 0.f;
#pragma unroll 5
    for (int i = 0; i < 50; i += 2) {
      a += b2f(s_lds[1 + r][base + i]) * wsv[base + i];
      a += b2f(s_lds[1 + r][base + i + 1]) * wsv[base + i + 1];
    }
    a += __shfl_xor(a, 1, 64);
    a += __shfl_xor(a, 2, 64);
    if ((tid & 3) == 0) sdot[r] = a + wsb;
  }
  __syncthreads();

  // ---- phase B: GEMM1 h = s @ (q*wsq)^T + lane-parallel row softmax ----
  {
    f32x4 acc0 = {0.f, 0.f, 0.f, 0.f}, acc1 = {0.f, 0.f, 0.f, 0.f};
#pragma unroll
    for (int kk = 0; kk < 7; ++kk) {
      short8 af = *(const short8*)&s_lds[1 + 16 * w + c][kk * 32 + g * 8];
      short8 b0 = *(const short8*)&qsw[c][kk * 32 + g * 8];
      short8 b1 = *(const short8*)&qsw[16 + c][kk * 32 + g * 8];
      acc0 = __builtin_amdgcn_mfma_f32_16x16x32_bf16(af, b0, acc0, 0, 0, 0);
      acc1 = __builtin_amdgcn_mfma_f32_16x16x32_bf16(af, b1, acc1, 0, 0, 0);
    }
    const int rbase = 16 * w + 4 * g;
    const float qd0 = qdot[c], qd1 = qdot[16 + c];
#pragma unroll
    for (int reg = 0; reg < 4; ++reg) {
      const int r = rbase + reg;
      const float s0 = sdot[r];
      float h0 = acc0[reg] + s0 + qd0;
      float h1 = (c < 14) ? (acc1[reg] + s0 + qd1) : -1e30f;
      float m = fmaxf(h0, h1);
#pragma unroll
      for (int msk = 1; msk < 16; msk <<= 1) m = fmaxf(m, __shfl_xor(m, msk, 64));
      float e0 = expf(h0 - m);
      float e1 = (c < 14) ? expf(h1 - m) : 0.f;
      float ssum = e0 + e1;
#pragma unroll
      for (int msk = 1; msk < 16; msk <<= 1) ssum += __shfl_xor(ssum, msk, 64);
      float inv = 1.f / ssum;
      a_bf[r][c]      = __float2bfloat16(e0 * inv);
      a_bf[r][16 + c] = __float2bfloat16(e1 * inv);
      if (c == 0) hmax[r] = m;
    }
  }
  __syncthreads();   // a_bf/hmax ready; qsw dead

  // ---- phase C: bvec (wave 0) || zero xstage (waves 1-7) ----
  if (w == 0) {
    float v0 = hmax[lane];
    float v1 = (lane < L_ - 64) ? hmax[64 + lane] : -1e30f;
    float m = wred_max64(fmaxf(v0, v1));
    float e0 = expf(v0 - m);
    float e1 = (lane < L_ - 64) ? expf(v1 - m) : 0.f;
    float inv = 1.f / wred_sum64(e0 + e1);
    bvec[lane] = e0 * inv;
    if (lane < L_ - 64) bvec[64 + lane] = e1 * inv;
  } else {
    const int4 z4 = {0, 0, 0, 0};
    for (int t = tid - 64; t < 3 * SROWS * XSTR * 2 / 16; t += 448) ((int4*)xstage)[t] = z4;
  }
  __syncthreads();
  {
    const int d = tid & 255, half = tid >> 8;
    if (d < D_) {
      const int lb = half * 60;
      float a0 = 0.f, a1 = 0.f, a2 = 0.f, a3 = 0.f;
      for (int l = 0; l < 60; l += 4) {
        a0 += bvec[lb + l]     * b2f(s_lds[1 + lb + l][d]);
        a1 += bvec[lb + l + 1] * b2f(s_lds[1 + lb + l + 1][d]);
        a2 += bvec[lb + l + 2] * b2f(s_lds[1 + lb + l + 2][d]);
        a3 += bvec[lb + l + 3] * b2f(s_lds[1 + lb + l + 3][d]);
      }
      q2p[half][d] = (a0 + a1) + (a2 + a3);
    }
  }
  __syncthreads();

  // ---- conv pipeline ----
  const short* wts = (const short*)wt;
  const short8 aft = *(const short8*)&a_bf[16 * w + c][g * 8];

  // stage(t): build x-tile t into buf. t<13: {x2 | x3} 16+16 cols; t=13: pos.
  auto STAGE = [&](int t, bf16 (*buf)[XSTR]) {
    if (t < 13) {
      short8 bfr = *(const short8*)&qT[t * 16 + c][g * 8];
      f32x4 o = __builtin_amdgcn_mfma_f32_16x16x32_bf16(aft, bfr, (f32x4){0.f,0.f,0.f,0.f}, 0, 0, 0);
#pragma unroll
      for (int reg = 0; reg < 4; ++reg) {
        const int r = 16 * w + 4 * g + reg;
        if (r < L_) {
          float sv = b2f(s_lds[1 + r][t * 16 + c]);
          buf[1 + r][c] = __float2bfloat16(sv * o[reg]);
        }
      }
#pragma unroll
      for (int e = tid; e < L_ * 16; e += 512) {
        const int r = e >> 4, cc = e & 15, dd = t * 16 + cc;
        float v = (dd < D_) ? b2f(s_lds[1 + r][dd]) * (q2p[0][dd] + q2p[1][dd]) : 0.f;
        buf[1 + r][16 + cc] = __float2bfloat16(v);
      }
    } else {
#pragma unroll
      for (int e = tid; e < SROWS * 32; e += 512) {
        const int r = e >> 5, cc = e & 31;
        bf16 v = __float2bfloat16(0.f);
        if (r >= 1 && r <= L_ && cc < 2 * P_) v = pos_lds[r - 1][cc];
        buf[r][cc] = v;
      }
    }
  };

  f32x4 acc[4][4];
#pragma unroll
  for (int i = 0; i < 4; ++i)
#pragma unroll
    for (int j = 0; j < 4; ++j) acc[i][j] = (f32x4){0.f, 0.f, 0.f, 0.f};

  STAGE(0, xstage[0]);

  for (int t = 0; t < 14; ++t) {
    // prefetch this tile's B frags (consumed after the barrier)
    short8 bw[3][4];
#pragma unroll
    for (int k = 0; k < 3; ++k)
#pragma unroll
      for (int ni = 0; ni < 4; ++ni)
        bw[k][ni] = *(const short8*)(
            wts + (((size_t)((k * NCH + 7 + t) * 16 + wn * 4 + ni)) << 9) + lane * 8);

    if (t < 13) STAGE(t + 1, xstage[(t + 1) % 3]);

    if (t < 7) {   // x1 chunk t: A straight from s_lds
      short8 af[3][4];
#pragma unroll
      for (int k = 0; k < 3; ++k)
#pragma unroll
        for (int mi = 0; mi < 4; ++mi)
          af[k][mi] = *(const short8*)&s_lds[wm * 64 + mi * 16 + c + k][t * 32 + g * 8];
#pragma unroll
      for (int k = 0; k < 3; ++k)
#pragma unroll
        for (int ni = 0; ni < 4; ++ni) {
          const short8 b1 = *(const short8*)(
              wts + (((size_t)((k * NCH + t) * 16 + wn * 4 + ni)) << 9) + lane * 8);
#pragma unroll
          for (int mi = 0; mi < 4; ++mi)
            acc[mi][ni] = __builtin_amdgcn_mfma_f32_16x16x32_bf16(af[k][mi], b1, acc[mi][ni], 0, 0, 0);
        }
    }
    __syncthreads();

    // conv on tile t from buf[t%3] using prefetched bw
    {
      bf16 (*buf)[XSTR] = xstage[t % 3];
      short8 afx[3][4];
#pragma unroll
      for (int k = 0; k < 3; ++k)
#pragma unroll
        for (int mi = 0; mi < 4; ++mi)
          afx[k][mi] = *(const short8*)&buf[wm * 64 + mi * 16 + c + k][g * 8];
#pragma unroll
      for (int k = 0; k < 3; ++k)
#pragma unroll
        for (int ni = 0; ni < 4; ++ni)
#pragma unroll
          for (int mi = 0; mi < 4; ++mi)
            acc[mi][ni] = __builtin_amdgcn_mfma_f32_16x16x32_bf16(afx[k][mi], bw[k][ni], acc[mi][ni], 0, 0, 0);
    }
  }

  // ---- epilogue: max over valid pos, +bias, relu -> feat ----
  const int pbase = wm * 64 + (g << 2);
#pragma unroll
  for (int ni = 0; ni < 4; ++ni) {
    float m = -1e30f;
#pragma unroll
    for (int mi = 0; mi < 4; ++mi)
#pragma unroll
      for (int reg = 0; reg < 4; ++reg) {
        int pos = pbase + mi * 16 + reg;
        if (pos < L_) m = fmaxf(m, acc[mi][ni][reg]);
      }
    m = fmaxf(m, __shfl_xor(m, 16, 64));
    m = fmaxf(m, __shfl_xor(m, 32, 64));
    if (g == 0) hred[w][ni * 16 + c] = m;
  }
  __syncthreads();
  for (int h = tid; h < H_; h += 512) {
    int wn2 = h >> 6, hl = h & 63;
    float m = fmaxf(hred[wn2][hl], hred[wn2 + 4][hl]);
    feat[(size_t)n * H_ + h] = fmaxf(0.f, m + conv_b[h]);
  }
}

// ---------------------------------------------------------------------------
// K3: bag self-attention + selective attention + final projection -> out [B][R]
// ---------------------------------------------------------------------------
__global__ __launch_bounds__(256) void k3_bag(
    const float* __restrict__ feat, const int* __restrict__ X_Rel,
    const float* __restrict__ rel_w, const float* __restrict__ rel_b,
    float* __restrict__ out)
{
  const int b = blockIdx.x;
  const int tid = threadIdx.x;
  __shared__ float f[BAG_][231];
  __shared__ float f2[BAG_][231];
  __shared__ float sc[BAG_][BAG_];
  __shared__ float relq[H_];
  __shared__ float zred[BAG_];
  __shared__ float wsel[BAG_];
  __shared__ float brep[H_];

  for (int t = tid; t < BAG_ * H_; t += 256) {
    int i = t / H_, h = t % H_;
    f[i][h] = feat[(size_t)(b * BAG_ + i) * H_ + h];
  }
  const int rel = X_Rel[b];
  for (int t = tid; t < H_; t += 256) relq[t] = rel_w[(size_t)rel * H_ + t];
  __syncthreads();

  if (tid < BAG_ * BAG_) {
    int i = tid >> 3, j = tid & 7;
    float acc = 0.f;
    for (int h = 0; h < H_; ++h) acc += f[i][h] * f[j][h];
    sc[i][j] = acc * (1.0f / sqrtf((float)H_));
  }
  __syncthreads();
  if (tid < BAG_) {
    float m = -1e30f;
    for (int j = 0; j < BAG_; ++j) m = fmaxf(m, sc[tid][j]);
    float s = 0.f;
    for (int j = 0; j < BAG_; ++j) { float e = expf(sc[tid][j] - m); sc[tid][j] = e; s += e; }
    float inv = 1.0f / s;
    for (int j = 0; j < BAG_; ++j) sc[tid][j] *= inv;
  }
  __syncthreads();
  for (int t = tid; t < BAG_ * H_; t += 256) {
    int i = t / H_, h = t % H_;
    float acc = 0.f;
#pragma unroll
    for (int j = 0; j < BAG_; ++j) acc += sc[i][j] * f[j][h];
    f2[i][h] = acc;
  }
  __syncthreads();
  if (tid < BAG_) {
    float acc = 0.f;
    for (int h = 0; h < H_; ++h) acc += f2[tid][h] * relq[h];
    zred[tid] = acc;
  }
  __syncthreads();
  if (tid == 0) {
    float m = -1e30f;
    for (int i = 0; i < BAG_; ++i) m = fmaxf(m, zred[i]);
    float s = 0.f;
    for (int i = 0; i < BAG_; ++i) { float e = expf(zred[i] - m); wsel[i] = e; s += e; }
    float inv = 1.0f / s;
    for (int i = 0; i < BAG_; ++i) wsel[i] *= inv;
  }
  __syncthreads();
  for (int t = tid; t < H_; t += 256) {
    float acc = 0.f;
#pragma unroll
    for (int i = 0; i < BAG_; ++i) acc += wsel[i] * f2[i][t];
    brep[t] = acc;
  }
  __syncthreads();
  if (tid < R_) {
    float acc = 0.f;
    for (int h = 0; h < H_; ++h) acc += brep[h] * rel_w[(size_t)tid * H_ + h];
    out[(size_t)b * R_ + tid] = acc + rel_b[tid];
  }
}

// ---------------------------------------------------------------------------
extern "C" void kernel_launch(void* const* d_in, const int* in_sizes, int n_in,
                              void* d_out, int out_size, void* d_ws, size_t ws_size,
                              hipStream_t stream)
{
  const int*   X        = (const int*)d_in[0];
  const int*   Q        = (const int*)d_in[1];
  const int*   P1       = (const int*)d_in[2];
  const int*   P2       = (const int*)d_in[3];
  // d_in[4] = X_Scope (uniform bags of 8; bag_id = i/8)
  const int*   X_Rel    = (const int*)d_in[5];
  const float* word_emb = (const float*)d_in[6];
  const float* pos1_emb = (const float*)d_in[7];
  const float* pos2_emb = (const float*)d_in[8];
  const float* ws_w     = (const float*)d_in[9];
  const float* ws_b     = (const float*)d_in[10];
  const float* wq_w     = (const float*)d_in[11];
  const float* wq_b     = (const float*)d_in[12];
  const float* wsq_w    = (const float*)d_in[13];
  // d_in[14] = wsq_b: uniform shift of h -> softmax-invariant (a and bvec), dropped
  const float* conv_w   = (const float*)d_in[15];
  const float* conv_b   = (const float*)d_in[16];
  const float* rel_w    = (const float*)d_in[17];
  const float* rel_b    = (const float*)d_in[18];

  // ws layout: feat f32 [N][H] | wt bf16 [3][21][16][64][8]
  const size_t feat_bytes = ((size_t)N_ * H_ * sizeof(float) + 255) & ~(size_t)255;
  float* feat = (float*)d_ws;
  bf16*  wt   = (bf16*)((char*)d_ws + feat_bytes);

  const int wt_elems = 3 * NCH * 16 * 64 * 8;   // 516096
  k0_prep_w<<<wt_elems / 256, 256, 0, stream>>>(conv_w, wt);
  kf_fused<<<N_, 512, 0, stream>>>(X, Q, P1, P2, word_emb, pos1_emb, pos2_emb,
                                   ws_w, ws_b, wq_w, wq_b, wsq_w, wt, conv_b, feat);
  k3_bag<<<B_, 256, 0, stream>>>(feat, X_Rel, rel_w, rel_b, (float*)d_out);
}